// Round 4
// baseline (2865.194 us; speedup 1.0000x reference)
//
#include <hip/hip_runtime.h>
#include <hip/hip_cooperative_groups.h>

namespace cg = cooperative_groups;

// Peeling propagation on bipartite graph. V=1e6, F=4.2e6, K=3 (edge e -> function e/3).
// T=5. Output: deg (V floats) in d_out.
//
// R12: dispatch-count collapse. Residual analysis of R9 (384us) and R11 (522us) shows
// ~15-17us fixed overhead PER DISPATCH dominating the iteration path (R11's frontier
// kernels did ~100x less work than R9's scans yet cost the same ~40us/iter). So:
//   kernel 1: k_pack_sort (R9-exact, 65us measured) + fused tmp/tgrp zeroing tail.
//   kernel 2: k_solve (COOPERATIVE): accum phase (direct offs reads, no transpose)
//             + 5 x (funcs-scan, grid.sync, update, grid.sync). R9 logic verbatim.
// 14 dispatches -> 2.

static constexpr int Vn = 1000000;
static constexpr int Fn = 4200000;
static constexpr int Tn = 5;

static constexpr int SBLK = 2048;                          // sort blocks / regions
static constexpr int FPB  = 2052;                          // functions/block (mult of 4)
static constexpr int BIN_BITS = 10;                        // fine bin = 1024 vars
static constexpr int BIN_SIZE = 1 << BIN_BITS;
static constexpr int NB  = (Vn + BIN_SIZE - 1) >> BIN_BITS;   // 977 fine bins
static constexpr int NBP = 1024;                           // padded fine-bin count (scan)
static constexpr int CH_BITS = 12;                         // chunk = 4096 vars
static constexpr int CH_SIZE = 1 << CH_BITS;
static constexpr int NCH = (Vn + CH_SIZE - 1) >> CH_BITS;  // 245 chunks
static constexpr int RCAP = 3 * FPB;                       // 6156 max entries/region
static constexpr int RSTRIDE = (RCAP + 63) & ~63;          // 6208 -> 128B-aligned regions
static constexpr int OROW = 1024;                          // offs row stride (u16)
static constexpr int AVW = NCH * (CH_SIZE / 64);           // 15680 u64 mask words

// ---- fused pack + histogram + shuffle-scan + LDS-staged scatter + coalesced flush ----
__global__ __launch_bounds__(256) void k_pack_sort(
    const int* __restrict__ vidx, const float* __restrict__ ef,
    const float* __restrict__ afunc,
    unsigned long long* __restrict__ gpack,
    unsigned short* __restrict__ offs,      // [SBLK][OROW] exclusive fine-bin offsets
    unsigned short* __restrict__ sorted,    // [SBLK][RSTRIDE] block-private regions
    unsigned int* __restrict__ tmp,         // zeroed in tail
    unsigned char* __restrict__ tgrp)       // zeroed in tail
{
    __shared__ unsigned int hist[NBP];
    __shared__ unsigned int cur[NBP];
    __shared__ unsigned int wsum[4];
    __shared__ unsigned int s_total;
    __shared__ __align__(16) unsigned short st[RSTRIDE];   // 12.4 KB staged region

    const int k = blockIdx.x;
    const int f0 = k * FPB;
    int n = Fn - f0; if (n < 0) n = 0; if (n > FPB) n = FPB;
    const int n4 = n >> 2;

    for (int i = threadIdx.x; i < NBP; i += 256) hist[i] = 0u;
    __syncthreads();

    // pass 1 (4-wide): read vidx/ef/afunc once, emit gpack, histogram fine bins
    for (int j = threadIdx.x; j < n4; j += 256) {
        const int fb = f0 + 4 * j, e = 3 * fb;
        int4 va = *(const int4*)(vidx + e);
        int4 vb = *(const int4*)(vidx + e + 4);
        int4 vc = *(const int4*)(vidx + e + 8);
        float4 ea = *(const float4*)(ef + e);
        float4 eb = *(const float4*)(ef + e + 4);
        float4 ec = *(const float4*)(ef + e + 8);
        float4 a4 = *(const float4*)(afunc + fb);
        int      vv[12] = {va.x, va.y, va.z, va.w, vb.x, vb.y, vb.z, vb.w, vc.x, vc.y, vc.z, vc.w};
        float    ss[12] = {ea.x, ea.y, ea.z, ea.w, eb.x, eb.y, eb.z, eb.w, ec.x, ec.y, ec.z, ec.w};
        float    aa[4]  = {a4.x, a4.y, a4.z, a4.w};
        unsigned long long gq[4];
        #pragma unroll
        for (int q = 0; q < 4; ++q) {
            int v0 = vv[3 * q], v1 = vv[3 * q + 1], v2 = vv[3 * q + 2];
            unsigned int s0 = ss[3 * q]     > 0.0f ? 1u : 0u;
            unsigned int s1 = ss[3 * q + 1] > 0.0f ? 1u : 0u;
            unsigned int s2 = ss[3 * q + 2] > 0.0f ? 1u : 0u;
            unsigned int act = aa[q] != 0.0f ? 1u : 0u;
            gq[q] = (unsigned long long)(unsigned int)v0
                  | ((unsigned long long)(unsigned int)v1 << 20)
                  | ((unsigned long long)(unsigned int)v2 << 40)
                  | ((unsigned long long)s0 << 60)
                  | ((unsigned long long)s1 << 61)
                  | ((unsigned long long)s2 << 62)
                  | ((unsigned long long)act << 63);
            if (act) {
                atomicAdd(&hist[v0 >> BIN_BITS], 1u);
                atomicAdd(&hist[v1 >> BIN_BITS], 1u);
                atomicAdd(&hist[v2 >> BIN_BITS], 1u);
            }
        }
        *(ulonglong2*)(gpack + fb)     = make_ulonglong2(gq[0], gq[1]);
        *(ulonglong2*)(gpack + fb + 2) = make_ulonglong2(gq[2], gq[3]);
    }
    // scalar tail (0..3 functions)
    for (int i = 4 * n4 + threadIdx.x; i < n; i += 256) {
        const int f = f0 + i, e0 = 3 * f;
        int v0 = vidx[e0], v1 = vidx[e0 + 1], v2 = vidx[e0 + 2];
        unsigned int s0 = ef[e0]     > 0.0f ? 1u : 0u;
        unsigned int s1 = ef[e0 + 1] > 0.0f ? 1u : 0u;
        unsigned int s2 = ef[e0 + 2] > 0.0f ? 1u : 0u;
        unsigned int act = afunc[f] != 0.0f ? 1u : 0u;
        unsigned long long g = (unsigned long long)(unsigned int)v0
                             | ((unsigned long long)(unsigned int)v1 << 20)
                             | ((unsigned long long)(unsigned int)v2 << 40)
                             | ((unsigned long long)s0 << 60)
                             | ((unsigned long long)s1 << 61)
                             | ((unsigned long long)s2 << 62)
                             | ((unsigned long long)act << 63);
        gpack[f] = g;
        if (act) {
            atomicAdd(&hist[v0 >> BIN_BITS], 1u);
            atomicAdd(&hist[v1 >> BIN_BITS], 1u);
            atomicAdd(&hist[v2 >> BIN_BITS], 1u);
        }
    }
    __syncthreads();

    // shuffle-based exclusive scan over 1024 fine bins (256 threads x 4 bins)
    {
        const int t = threadIdx.x, lane = t & 63, wid = t >> 6;
        unsigned int a0 = hist[4 * t], a1 = hist[4 * t + 1];
        unsigned int a2 = hist[4 * t + 2], a3 = hist[4 * t + 3];
        unsigned int tsum = a0 + a1 + a2 + a3;
        unsigned int x = tsum;
        #pragma unroll
        for (int off = 1; off < 64; off <<= 1) {
            unsigned int y = (unsigned int)__shfl_up((int)x, off);
            if (lane >= off) x += y;
        }
        if (lane == 63) wsum[wid] = x;
        __syncthreads();
        unsigned int wbase = 0;
        for (int w = 0; w < wid; ++w) wbase += wsum[w];
        unsigned int e0x = wbase + x - tsum;      // exclusive prefix of bin 4t
        unsigned int e1x = e0x + a0, e2x = e1x + a1, e3x = e2x + a2;
        cur[4 * t] = e0x; cur[4 * t + 1] = e1x; cur[4 * t + 2] = e2x; cur[4 * t + 3] = e3x;
        if (t == 255) s_total = e3x + a3;         // inclusive total (= #active entries)
        unsigned short* row = offs + (size_t)k * OROW;
        if (4 * t     <= NB) row[4 * t]     = (unsigned short)e0x;
        if (4 * t + 1 <= NB) row[4 * t + 1] = (unsigned short)e1x;
        if (4 * t + 2 <= NB) row[4 * t + 2] = (unsigned short)e2x;
        if (4 * t + 3 <= NB) row[4 * t + 3] = (unsigned short)e3x;
    }
    __syncthreads();

    // pass 2 (4-wide): re-read gpack (cache-hot) and scatter into LDS region;
    // entry = 12-bit chunk-local v | sign<<12
    for (int j = threadIdx.x; j < n4; j += 256) {
        const int fb = f0 + 4 * j;
        ulonglong2 ga = *(const ulonglong2*)(gpack + fb);
        ulonglong2 gb = *(const ulonglong2*)(gpack + fb + 2);
        unsigned long long gq[4] = {ga.x, ga.y, gb.x, gb.y};
        #pragma unroll
        for (int q = 0; q < 4; ++q) {
            unsigned long long g = gq[q];
            if ((long long)g < 0) {
                unsigned int v0 = (unsigned int)(g & 0xFFFFFu);
                unsigned int v1 = (unsigned int)((g >> 20) & 0xFFFFFu);
                unsigned int v2 = (unsigned int)((g >> 40) & 0xFFFFFu);
                unsigned int sl0 = atomicAdd(&cur[v0 >> BIN_BITS], 1u);
                st[sl0] = (unsigned short)((v0 & (CH_SIZE - 1)) | ((unsigned int)((g >> 60) & 1u) << CH_BITS));
                unsigned int sl1 = atomicAdd(&cur[v1 >> BIN_BITS], 1u);
                st[sl1] = (unsigned short)((v1 & (CH_SIZE - 1)) | ((unsigned int)((g >> 61) & 1u) << CH_BITS));
                unsigned int sl2 = atomicAdd(&cur[v2 >> BIN_BITS], 1u);
                st[sl2] = (unsigned short)((v2 & (CH_SIZE - 1)) | ((unsigned int)((g >> 62) & 1u) << CH_BITS));
            }
        }
    }
    for (int i = 4 * n4 + threadIdx.x; i < n; i += 256) {
        unsigned long long g = gpack[f0 + i];
        if ((long long)g < 0) {
            unsigned int v0 = (unsigned int)(g & 0xFFFFFu);
            unsigned int v1 = (unsigned int)((g >> 20) & 0xFFFFFu);
            unsigned int v2 = (unsigned int)((g >> 40) & 0xFFFFFu);
            unsigned int sl0 = atomicAdd(&cur[v0 >> BIN_BITS], 1u);
            st[sl0] = (unsigned short)((v0 & (CH_SIZE - 1)) | ((unsigned int)((g >> 60) & 1u) << CH_BITS));
            unsigned int sl1 = atomicAdd(&cur[v1 >> BIN_BITS], 1u);
            st[sl1] = (unsigned short)((v1 & (CH_SIZE - 1)) | ((unsigned int)((g >> 61) & 1u) << CH_BITS));
            unsigned int sl2 = atomicAdd(&cur[v2 >> BIN_BITS], 1u);
            st[sl2] = (unsigned short)((v2 & (CH_SIZE - 1)) | ((unsigned int)((g >> 62) & 1u) << CH_BITS));
        }
    }
    __syncthreads();

    // coalesced flush: LDS region -> global, 16B vectors (slack beyond total never read)
    {
        const int tot = (int)s_total;
        const int nvec = (tot + 7) >> 3;               // 8 u16 per int4
        int4* __restrict__ dst = (int4*)(sorted + (size_t)k * RSTRIDE);  // RSTRIDE*2 % 16 == 0
        const int4* __restrict__ src = (const int4*)st;
        for (int i = threadIdx.x; i < nvec; i += 256) dst[i] = src[i];
    }

    // fused tail: zero tmp (4MB) and tgrp (15.7KB) for the solve kernel
    {
        const int gt = blockIdx.x * 256 + threadIdx.x;
        const int gs = SBLK * 256;
        for (int i = gt; i < Vn; i += gs) tmp[i] = 0u;
        for (int i = gt; i < AVW; i += gs) tgrp[i] = 0;
    }
}

// ---- iteration helper: function side (R9 logic verbatim) ----
__device__ __forceinline__ void fire_one(unsigned long long g, int f,
                                         unsigned long long* __restrict__ gpack,
                                         const unsigned int* __restrict__ svm32,
                                         const unsigned char* __restrict__ sgrp,
                                         unsigned int* __restrict__ tmp,
                                         unsigned char* __restrict__ tgrp)
{
    if ((long long)g >= 0) return;               // inactive (bit63 clear)
    unsigned int v0 = (unsigned int)(g & 0xFFFFFu);
    unsigned int v1 = (unsigned int)((g >> 20) & 0xFFFFFu);
    unsigned int v2 = (unsigned int)((g >> 40) & 0xFFFFFu);
    // L1-resident group filter (15.7 KB): skip fine L2 probes when no 64-var group has a single
    if (!(sgrp[v0 >> 6] | sgrp[v1 >> 6] | sgrp[v2 >> 6])) return;
    unsigned int hit = ((svm32[v0 >> 5] >> (v0 & 31u)) |
                        (svm32[v1 >> 5] >> (v1 & 31u)) |
                        (svm32[v2 >> 5] >> (v2 & 31u))) & 1u;
    if (!hit) return;
    gpack[f] = g & ~(1ull << 63);                // function deactivates (single_f = 1)
    atomicAdd(&tmp[v0], 0x10000u | (unsigned int)((g >> 60) & 1u));
    atomicAdd(&tmp[v1], 0x10000u | (unsigned int)((g >> 61) & 1u));
    atomicAdd(&tmp[v2], 0x10000u | (unsigned int)((g >> 62) & 1u));
    tgrp[v0 >> 6] = 1; tgrp[v1 >> 6] = 1; tgrp[v2 >> 6] = 1;
}

// ---- ONE cooperative kernel: accum + 5 x (funcs-scan, sync, update, sync) ----
__global__ __launch_bounds__(256, 8) void k_solve(
    const unsigned short* __restrict__ offs,
    const unsigned short* __restrict__ sorted,
    const float* __restrict__ avars,
    unsigned int* __restrict__ packed,
    unsigned long long* __restrict__ avm,
    unsigned long long* __restrict__ svm,
    unsigned char* __restrict__ sgrp,
    unsigned char* __restrict__ tgrp,
    unsigned int* __restrict__ tmp,
    unsigned long long* __restrict__ gpack,
    float* __restrict__ deg)
{
    cg::grid_group grid = cg::this_grid();
    __shared__ unsigned int acc[CH_SIZE];        // 16 KB
    const int gtid = blockIdx.x * 256 + threadIdx.x;
    const int nthr = gridDim.x * 256;            // multiple of 64

    // ---- phase A: per-chunk accumulate + decode (grid-stride over 245 chunks) ----
    for (int c = blockIdx.x; c < NCH; c += gridDim.x) {
        for (int i = threadIdx.x; i < CH_SIZE; i += 256) acc[i] = 0u;
        __syncthreads();
        const int r0 = 4 * c;
        const int r1 = (4 * c + 4 < NB) ? (4 * c + 4) : NB;
        for (int k = threadIdx.x; k < SBLK; k += 256) {
            const int s0 = offs[(size_t)k * OROW + r0];   // direct read (L2-hot, 1-2 readers/elem)
            const int s1 = offs[(size_t)k * OROW + r1];
            const unsigned short* seg = sorted + (size_t)k * RSTRIDE;  // 128B-aligned base
            int e = s0;
            for (; e < s1 && (e & 3); ++e) {
                unsigned int p = seg[e];
                atomicAdd(&acc[p & (CH_SIZE - 1)], 0x10000u | (p >> CH_BITS));
            }
            for (; e + 4 <= s1; e += 4) {
                unsigned long long q = *(const unsigned long long*)(seg + e);
                #pragma unroll
                for (int j = 0; j < 4; ++j) {
                    unsigned int p = (unsigned int)((q >> (16 * j)) & 0xFFFFu);
                    atomicAdd(&acc[p & (CH_SIZE - 1)], 0x10000u | (p >> CH_BITS));
                }
            }
            for (; e < s1; ++e) {
                unsigned int p = seg[e];
                atomicAdd(&acc[p & (CH_SIZE - 1)], 0x10000u | (p >> CH_BITS));
            }
        }
        __syncthreads();
        const int vbase = c << CH_BITS;
        for (int i = threadIdx.x; i < CH_SIZE; i += 256) {
            int v = vbase + i;
            bool valid = v < Vn;
            unsigned int p = valid ? acc[i] : 0u;
            bool av = valid && (avars[v] != 0.0f);
            unsigned int cnt = p >> 16, pos = p & 0xFFFFu;
            bool sv = av && (pos == 0u || pos == cnt);    // deg == |sdeg|
            unsigned long long avb = __ballot(av);
            unsigned long long svb = __ballot(sv);
            if (valid) packed[v] = p;
            if ((threadIdx.x & 63) == 0) {
                avm[v >> 6] = avb;
                svm[v >> 6] = svb;
                sgrp[v >> 6] = (svb != 0ull) ? 1 : 0;
            }
        }
        __syncthreads();                          // acc reused next chunk
    }
    grid.sync();

    // ---- phases B/C x Tn: funcs scan, update ----
    const unsigned int* svm32 = (const unsigned int*)svm;
    for (int t = 0; t < Tn; ++t) {
        // funcs: 4 fns/thread, group filter then fine bitmask
        for (int q = gtid; q < Fn / 4; q += nthr) {
            const int f = 4 * q;
            ulonglong2 g2 = *(const ulonglong2*)(gpack + f);   // 16B aligned
            ulonglong2 g3 = *(const ulonglong2*)(gpack + f + 2);
            fire_one(g2.x, f,     gpack, svm32, sgrp, tmp, tgrp);
            fire_one(g2.y, f + 1, gpack, svm32, sgrp, tmp, tgrp);
            fire_one(g3.x, f + 2, gpack, svm32, sgrp, tmp, tgrp);
            fire_one(g3.y, f + 3, gpack, svm32, sgrp, tmp, tgrp);
        }
        grid.sync();

        // update: packed -= tmp (av-gated, tgrp-skipped); masks refresh
        const bool wd = (t == Tn - 1);
        for (int v = gtid; v < Vn; v += nthr) {   // nthr % 64 == 0: lanes stay word-aligned
            const int lane = threadIdx.x & 63;
            unsigned long long avw = avm[v >> 6], svw = svm[v >> 6];
            unsigned char tg = tgrp[v >> 6];
            if (!wd && !tg && svw == 0ull) continue;   // clean word (wave-uniform)
            bool av_old = (avw >> lane) & 1ull;
            bool sv     = (svw >> lane) & 1ull;
            bool av_new = av_old && !sv;
            unsigned int p = packed[v];
            if (tg) {
                unsigned int tp = tmp[v];
                if (tp != 0u) {
                    if (av_old) { p -= tp; packed[v] = p; }
                    tmp[v] = 0u;
                }
            }
            unsigned int c = p >> 16, pos = p & 0xFFFFu;
            bool nsv = av_new && (pos == 0u || pos == c);
            unsigned long long nsvb = __ballot(nsv);
            if (lane == 0) {
                svm[v >> 6] = nsvb;
                avm[v >> 6] = avw & ~svw;
                sgrp[v >> 6] = (nsvb != 0ull) ? 1 : 0;
                if (tg) tgrp[v >> 6] = 0;
            }
            if (wd) deg[v] = (float)c;
        }
        grid.sync();
    }
}

extern "C" void kernel_launch(void* const* d_in, const int* in_sizes, int n_in,
                              void* d_out, int out_size, void* d_ws, size_t ws_size,
                              hipStream_t stream) {
    const int*   graph_map        = (const int*)d_in[0];   // row0 = vidx
    const float* edge_feature     = (const float*)d_in[1];
    const float* active_variables = (const float*)d_in[2];
    const float* active_functions = (const float*)d_in[3];
    const int* vidx = graph_map;

    float* deg = (float*)d_out;
    char* ws = (char*)d_ws;
    size_t off = 0;
    auto alloc = [&](size_t bytes) -> void* {
        void* p = ws + off; off += (bytes + 255) & ~(size_t)255; return p;
    };
    unsigned long long* gpack = (unsigned long long*)alloc(8ull * Fn);            // 33.6 MB
    unsigned int* packed      = (unsigned int*)alloc(4ull * Vn);                  //  4.0 MB
    unsigned long long* avm   = (unsigned long long*)alloc(8ull * AVW);           //  125 KB
    unsigned long long* svm   = (unsigned long long*)alloc(8ull * AVW);           //  125 KB
    unsigned char* sgrp       = (unsigned char*)alloc(AVW);                       // 15.7 KB
    unsigned char* tgrp       = (unsigned char*)alloc(AVW);                       // 15.7 KB
    unsigned short* offs      = (unsigned short*)alloc(2ull * SBLK * OROW);       //  4.2 MB
    unsigned short* sorted    = (unsigned short*)alloc(2ull * SBLK * RSTRIDE);    // 25.4 MB
    unsigned int* tmp         = (unsigned int*)alloc(4ull * Vn);                  //  4.0 MB
    // total ~71.5 MB

    // cooperative grid sizing (host-side queries are graph-capture-safe; cached)
    static int grid_blocks = 0;
    if (grid_blocks == 0) {
        int dev = 0; hipGetDevice(&dev);
        int cus = 0; hipDeviceGetAttribute(&cus, hipDeviceAttributeMultiprocessorCount, dev);
        int nb = 0;
        hipOccupancyMaxActiveBlocksPerMultiprocessor(&nb, k_solve, 256, 0);
        if (nb < 1) nb = 1;
        if (cus < 1) cus = 256;
        long long g = (long long)nb * cus;
        if (g > 2048) g = 2048;
        if (g < 256) g = 256;                     // must cover NCH=245 chunk tasks amply
        grid_blocks = (int)g;
    }

    k_pack_sort<<<SBLK, 256, 0, stream>>>(vidx, edge_feature, active_functions,
                                          gpack, offs, sorted, tmp, tgrp);

    void* args[] = {
        (void*)&offs, (void*)&sorted, (void*)&active_variables, (void*)&packed,
        (void*)&avm, (void*)&svm, (void*)&sgrp, (void*)&tgrp,
        (void*)&tmp, (void*)&gpack, (void*)&deg
    };
    hipLaunchCooperativeKernel(k_solve, dim3(grid_blocks), dim3(256), args, 0, stream);
}

// Round 5
// 312.314 us; speedup vs baseline: 9.1741x; 9.1741x over previous
//
#include <hip/hip_runtime.h>

// Peeling propagation on bipartite graph. V=1e6, F=4.2e6, K=3 (edge e -> function e/3).
// T=5. Output: deg (V floats) in d_out.
//
// R13: revert R12's cooperative kernel (grid.sync measured ~240us each -> 2673us; launch
// boundaries are ~5-15us, NOT the bottleneck). Base = R10 (384us) plus:
//  * sgrp -> sgrp8: byte holds 8-var-granular dirty bits (8x sharper filter), and
//    k_funcs preloads it into LDS (15.7KB): kills the 12.6M random L1 byte-probe
//    transaction storm (~20us/iter) AND cuts svm L2 confirms ~6x.
//  * k_funcs: 8 fns/thread (halves blocks -> halves LDS preload traffic).
//  * k_zero_tmp fused into k_pack_sort tail (tmp now its own buffer, no alias).
//  * k_update: clean-word early-exit (stale-skip proven consistent).

static constexpr int Vn = 1000000;
static constexpr int Fn = 4200000;
static constexpr int Tn = 5;

static constexpr int SBLK = 2048;                          // sort blocks / regions
static constexpr int FPB  = 2052;                          // functions/block (mult of 4)
static constexpr int BIN_BITS = 10;                        // fine bin = 1024 vars
static constexpr int BIN_SIZE = 1 << BIN_BITS;
static constexpr int NB  = (Vn + BIN_SIZE - 1) >> BIN_BITS;   // 977 fine bins
static constexpr int NBP = 1024;                           // padded fine-bin count (scan)
static constexpr int CH_BITS = 12;                         // chunk = 4096 vars
static constexpr int CH_SIZE = 1 << CH_BITS;
static constexpr int NCH = (Vn + CH_SIZE - 1) >> CH_BITS;  // 245 chunks
static constexpr int RCAP = 3 * FPB;                       // 6156 max entries/region
static constexpr int RSTRIDE = (RCAP + 63) & ~63;          // 6208 -> 128B-aligned regions
static constexpr int OROW = 1024;                          // offs row stride (u16)
static constexpr int AVW = NCH * (CH_SIZE / 64);           // 15680 u64 mask words (16B-mult)

// ---- fused pack + histogram + shuffle-scan + LDS-staged scatter + coalesced flush ----
__global__ __launch_bounds__(256) void k_pack_sort(
    const int* __restrict__ vidx, const float* __restrict__ ef,
    const float* __restrict__ afunc,
    unsigned long long* __restrict__ gpack,
    unsigned short* __restrict__ offs,      // [SBLK][OROW] exclusive fine-bin offsets
    unsigned short* __restrict__ sorted,    // [SBLK][RSTRIDE] block-private regions
    unsigned int* __restrict__ tmp,         // zeroed in tail (own buffer, no alias)
    unsigned char* __restrict__ tgrp)       // zeroed in tail
{
    __shared__ unsigned int hist[NBP];
    __shared__ unsigned int cur[NBP];
    __shared__ unsigned int wsum[4];
    __shared__ unsigned int s_total;
    __shared__ __align__(16) unsigned short st[RSTRIDE];   // 12.4 KB staged region

    const int k = blockIdx.x;
    const int f0 = k * FPB;
    int n = Fn - f0; if (n < 0) n = 0; if (n > FPB) n = FPB;
    const int n4 = n >> 2;

    for (int i = threadIdx.x; i < NBP; i += 256) hist[i] = 0u;
    __syncthreads();

    // pass 1 (4-wide): read vidx/ef/afunc once, emit gpack, histogram fine bins
    for (int j = threadIdx.x; j < n4; j += 256) {
        const int fb = f0 + 4 * j, e = 3 * fb;
        int4 va = *(const int4*)(vidx + e);
        int4 vb = *(const int4*)(vidx + e + 4);
        int4 vc = *(const int4*)(vidx + e + 8);
        float4 ea = *(const float4*)(ef + e);
        float4 eb = *(const float4*)(ef + e + 4);
        float4 ec = *(const float4*)(ef + e + 8);
        float4 a4 = *(const float4*)(afunc + fb);
        int      vv[12] = {va.x, va.y, va.z, va.w, vb.x, vb.y, vb.z, vb.w, vc.x, vc.y, vc.z, vc.w};
        float    ss[12] = {ea.x, ea.y, ea.z, ea.w, eb.x, eb.y, eb.z, eb.w, ec.x, ec.y, ec.z, ec.w};
        float    aa[4]  = {a4.x, a4.y, a4.z, a4.w};
        unsigned long long gq[4];
        #pragma unroll
        for (int q = 0; q < 4; ++q) {
            int v0 = vv[3 * q], v1 = vv[3 * q + 1], v2 = vv[3 * q + 2];
            unsigned int s0 = ss[3 * q]     > 0.0f ? 1u : 0u;
            unsigned int s1 = ss[3 * q + 1] > 0.0f ? 1u : 0u;
            unsigned int s2 = ss[3 * q + 2] > 0.0f ? 1u : 0u;
            unsigned int act = aa[q] != 0.0f ? 1u : 0u;
            gq[q] = (unsigned long long)(unsigned int)v0
                  | ((unsigned long long)(unsigned int)v1 << 20)
                  | ((unsigned long long)(unsigned int)v2 << 40)
                  | ((unsigned long long)s0 << 60)
                  | ((unsigned long long)s1 << 61)
                  | ((unsigned long long)s2 << 62)
                  | ((unsigned long long)act << 63);
            if (act) {
                atomicAdd(&hist[v0 >> BIN_BITS], 1u);
                atomicAdd(&hist[v1 >> BIN_BITS], 1u);
                atomicAdd(&hist[v2 >> BIN_BITS], 1u);
            }
        }
        *(ulonglong2*)(gpack + fb)     = make_ulonglong2(gq[0], gq[1]);
        *(ulonglong2*)(gpack + fb + 2) = make_ulonglong2(gq[2], gq[3]);
    }
    // scalar tail (0..3 functions)
    for (int i = 4 * n4 + threadIdx.x; i < n; i += 256) {
        const int f = f0 + i, e0 = 3 * f;
        int v0 = vidx[e0], v1 = vidx[e0 + 1], v2 = vidx[e0 + 2];
        unsigned int s0 = ef[e0]     > 0.0f ? 1u : 0u;
        unsigned int s1 = ef[e0 + 1] > 0.0f ? 1u : 0u;
        unsigned int s2 = ef[e0 + 2] > 0.0f ? 1u : 0u;
        unsigned int act = afunc[f] != 0.0f ? 1u : 0u;
        unsigned long long g = (unsigned long long)(unsigned int)v0
                             | ((unsigned long long)(unsigned int)v1 << 20)
                             | ((unsigned long long)(unsigned int)v2 << 40)
                             | ((unsigned long long)s0 << 60)
                             | ((unsigned long long)s1 << 61)
                             | ((unsigned long long)s2 << 62)
                             | ((unsigned long long)act << 63);
        gpack[f] = g;
        if (act) {
            atomicAdd(&hist[v0 >> BIN_BITS], 1u);
            atomicAdd(&hist[v1 >> BIN_BITS], 1u);
            atomicAdd(&hist[v2 >> BIN_BITS], 1u);
        }
    }
    __syncthreads();

    // shuffle-based exclusive scan over 1024 fine bins (256 threads x 4 bins)
    {
        const int t = threadIdx.x, lane = t & 63, wid = t >> 6;
        unsigned int a0 = hist[4 * t], a1 = hist[4 * t + 1];
        unsigned int a2 = hist[4 * t + 2], a3 = hist[4 * t + 3];
        unsigned int tsum = a0 + a1 + a2 + a3;
        unsigned int x = tsum;
        #pragma unroll
        for (int off = 1; off < 64; off <<= 1) {
            unsigned int y = (unsigned int)__shfl_up((int)x, off);
            if (lane >= off) x += y;
        }
        if (lane == 63) wsum[wid] = x;
        __syncthreads();
        unsigned int wbase = 0;
        for (int w = 0; w < wid; ++w) wbase += wsum[w];
        unsigned int e0x = wbase + x - tsum;      // exclusive prefix of bin 4t
        unsigned int e1x = e0x + a0, e2x = e1x + a1, e3x = e2x + a2;
        cur[4 * t] = e0x; cur[4 * t + 1] = e1x; cur[4 * t + 2] = e2x; cur[4 * t + 3] = e3x;
        if (t == 255) s_total = e3x + a3;         // inclusive total (= #active entries)
        unsigned short* row = offs + (size_t)k * OROW;
        if (4 * t     <= NB) row[4 * t]     = (unsigned short)e0x;
        if (4 * t + 1 <= NB) row[4 * t + 1] = (unsigned short)e1x;
        if (4 * t + 2 <= NB) row[4 * t + 2] = (unsigned short)e2x;
        if (4 * t + 3 <= NB) row[4 * t + 3] = (unsigned short)e3x;
    }
    __syncthreads();

    // pass 2 (4-wide): re-read gpack (cache-hot) and scatter into LDS region;
    // entry = 12-bit chunk-local v | sign<<12
    for (int j = threadIdx.x; j < n4; j += 256) {
        const int fb = f0 + 4 * j;
        ulonglong2 ga = *(const ulonglong2*)(gpack + fb);
        ulonglong2 gb = *(const ulonglong2*)(gpack + fb + 2);
        unsigned long long gq[4] = {ga.x, ga.y, gb.x, gb.y};
        #pragma unroll
        for (int q = 0; q < 4; ++q) {
            unsigned long long g = gq[q];
            if ((long long)g < 0) {
                unsigned int v0 = (unsigned int)(g & 0xFFFFFu);
                unsigned int v1 = (unsigned int)((g >> 20) & 0xFFFFFu);
                unsigned int v2 = (unsigned int)((g >> 40) & 0xFFFFFu);
                unsigned int sl0 = atomicAdd(&cur[v0 >> BIN_BITS], 1u);
                st[sl0] = (unsigned short)((v0 & (CH_SIZE - 1)) | ((unsigned int)((g >> 60) & 1u) << CH_BITS));
                unsigned int sl1 = atomicAdd(&cur[v1 >> BIN_BITS], 1u);
                st[sl1] = (unsigned short)((v1 & (CH_SIZE - 1)) | ((unsigned int)((g >> 61) & 1u) << CH_BITS));
                unsigned int sl2 = atomicAdd(&cur[v2 >> BIN_BITS], 1u);
                st[sl2] = (unsigned short)((v2 & (CH_SIZE - 1)) | ((unsigned int)((g >> 62) & 1u) << CH_BITS));
            }
        }
    }
    for (int i = 4 * n4 + threadIdx.x; i < n; i += 256) {
        unsigned long long g = gpack[f0 + i];
        if ((long long)g < 0) {
            unsigned int v0 = (unsigned int)(g & 0xFFFFFu);
            unsigned int v1 = (unsigned int)((g >> 20) & 0xFFFFFu);
            unsigned int v2 = (unsigned int)((g >> 40) & 0xFFFFFu);
            unsigned int sl0 = atomicAdd(&cur[v0 >> BIN_BITS], 1u);
            st[sl0] = (unsigned short)((v0 & (CH_SIZE - 1)) | ((unsigned int)((g >> 60) & 1u) << CH_BITS));
            unsigned int sl1 = atomicAdd(&cur[v1 >> BIN_BITS], 1u);
            st[sl1] = (unsigned short)((v1 & (CH_SIZE - 1)) | ((unsigned int)((g >> 61) & 1u) << CH_BITS));
            unsigned int sl2 = atomicAdd(&cur[v2 >> BIN_BITS], 1u);
            st[sl2] = (unsigned short)((v2 & (CH_SIZE - 1)) | ((unsigned int)((g >> 62) & 1u) << CH_BITS));
        }
    }
    __syncthreads();

    // coalesced flush: LDS region -> global, 16B vectors (slack beyond total never read)
    {
        const int tot = (int)s_total;
        const int nvec = (tot + 7) >> 3;               // 8 u16 per int4
        int4* __restrict__ dst = (int4*)(sorted + (size_t)k * RSTRIDE);  // RSTRIDE*2 % 16 == 0
        const int4* __restrict__ src = (const int4*)st;
        for (int i = threadIdx.x; i < nvec; i += 256) dst[i] = src[i];
    }

    // fused tail: zero tmp (4MB) and tgrp for the iteration kernels
    {
        const int gt = blockIdx.x * 256 + threadIdx.x;
        const int gs = SBLK * 256;
        for (int i = gt; i < Vn; i += gs) tmp[i] = 0u;
        for (int i = gt; i < AVW; i += gs) tgrp[i] = 0;
    }
}

// ---- tiled transpose: offs [SBLK][1024] -> offs_T [1024][SBLK] ----
__global__ __launch_bounds__(256) void k_transpose(const unsigned short* __restrict__ in,
                                                   unsigned short* __restrict__ out) {
    __shared__ unsigned short t[64][65];
    const int bx = blockIdx.x;   // 16 col tiles (1024/64)
    const int by = blockIdx.y;   // 32 row tiles (2048/64)
    for (int i = threadIdx.x; i < 64 * 64; i += 256) {
        int r = i >> 6, c = i & 63;
        t[r][c] = in[(size_t)(by * 64 + r) * OROW + (bx * 64 + c)];
    }
    __syncthreads();
    for (int i = threadIdx.x; i < 64 * 64; i += 256) {
        int r = i >> 6, c = i & 63;
        out[(size_t)(bx * 64 + r) * SBLK + (by * 64 + c)] = t[c][r];
    }
}

// sub-byte dirty mask from a 64-bit singles word: bit j = (byte j of m) != 0
__device__ __forceinline__ unsigned char subdirty8(unsigned long long m) {
    unsigned char b = 0;
    #pragma unroll
    for (int j = 0; j < 8; ++j) b |= (unsigned char)((((m >> (8 * j)) & 0xFFull) ? 1u : 0u) << j);
    return b;
}

// ---- per-chunk accumulate + decode. Thread-per-region, contiguous spans, u64 loads. ----
__global__ __launch_bounds__(1024) void k_accum(
    const unsigned short* __restrict__ offs_T,   // [1024][SBLK]
    const unsigned short* __restrict__ sorted,
    const float* __restrict__ avars,
    unsigned int* __restrict__ packed,
    unsigned long long* __restrict__ avm,
    unsigned long long* __restrict__ svm,
    unsigned char* __restrict__ sgrp8)
{
    __shared__ unsigned int acc[CH_SIZE];        // 16 KB
    __shared__ unsigned short row0[SBLK];        // 4 KB
    __shared__ unsigned short row1[SBLK];        // 4 KB
    const int c = blockIdx.x;                    // chunk 0..244
    const int r0 = 4 * c;
    const int r1 = (4 * c + 4 < NB) ? (4 * c + 4) : NB;
    for (int i = threadIdx.x; i < CH_SIZE; i += 1024) acc[i] = 0u;
    for (int i = threadIdx.x; i < SBLK; i += 1024) {
        row0[i] = offs_T[(size_t)r0 * SBLK + i];
        row1[i] = offs_T[(size_t)r1 * SBLK + i];
    }
    __syncthreads();
    for (int k = threadIdx.x; k < SBLK; k += 1024) {   // 2 regions per thread
        const int s0 = row0[k], s1 = row1[k];
        const unsigned short* seg = sorted + (size_t)k * RSTRIDE;  // 128B-aligned base
        int e = s0;
        for (; e < s1 && (e & 3); ++e) {               // head to 8B alignment
            unsigned int p = seg[e];
            atomicAdd(&acc[p & (CH_SIZE - 1)], 0x10000u | (p >> CH_BITS));
        }
        for (; e + 4 <= s1; e += 4) {                  // 4 entries per u64 load
            unsigned long long q = *(const unsigned long long*)(seg + e);
            #pragma unroll
            for (int j = 0; j < 4; ++j) {
                unsigned int p = (unsigned int)((q >> (16 * j)) & 0xFFFFu);
                atomicAdd(&acc[p & (CH_SIZE - 1)], 0x10000u | (p >> CH_BITS));
            }
        }
        for (; e < s1; ++e) {                          // tail
            unsigned int p = seg[e];
            atomicAdd(&acc[p & (CH_SIZE - 1)], 0x10000u | (p >> CH_BITS));
        }
    }
    __syncthreads();
    const int vbase = c << CH_BITS;
    for (int i = threadIdx.x; i < CH_SIZE; i += 1024) {
        int v = vbase + i;
        bool valid = v < Vn;
        unsigned int p = valid ? acc[i] : 0u;
        bool av = valid && (avars[v] != 0.0f);
        unsigned int cnt = p >> 16, pos = p & 0xFFFFu;
        bool sv = av && (pos == 0u || pos == cnt);    // deg == |sdeg|
        unsigned long long avb = __ballot(av);
        unsigned long long svb = __ballot(sv);
        if (valid) packed[v] = p;
        if ((threadIdx.x & 63) == 0) {                // word index < AVW (chunk-padded)
            avm[v >> 6] = avb;
            svm[v >> 6] = svb;
            sgrp8[v >> 6] = subdirty8(svb);           // 8-var-granular dirty bits
        }
    }
}

// ---- iteration: function side. 8 fns/thread; LDS sgrp8 filter then fine bitmask. ----
__device__ __forceinline__ void fire_one(unsigned long long g, int f,
                                         unsigned long long* __restrict__ gpack,
                                         const unsigned int* __restrict__ svm32,
                                         const unsigned char* __restrict__ s8,   // LDS
                                         unsigned int* __restrict__ tmp,
                                         unsigned char* __restrict__ tgrp)
{
    if ((long long)g >= 0) return;               // inactive (bit63 clear)
    unsigned int v0 = (unsigned int)(g & 0xFFFFFu);
    unsigned int v1 = (unsigned int)((g >> 20) & 0xFFFFFu);
    unsigned int v2 = (unsigned int)((g >> 40) & 0xFFFFFu);
    // LDS-resident 8-var-granular filter: no global transactions on the common path
    unsigned int h0 = (unsigned int)(s8[v0 >> 6] >> ((v0 >> 3) & 7u)) & 1u;
    unsigned int h1 = (unsigned int)(s8[v1 >> 6] >> ((v1 >> 3) & 7u)) & 1u;
    unsigned int h2 = (unsigned int)(s8[v2 >> 6] >> ((v2 >> 3) & 7u)) & 1u;
    if (!(h0 | h1 | h2)) return;
    unsigned int hit = ((svm32[v0 >> 5] >> (v0 & 31u)) |
                        (svm32[v1 >> 5] >> (v1 & 31u)) |
                        (svm32[v2 >> 5] >> (v2 & 31u))) & 1u;
    if (!hit) return;
    gpack[f] = g & ~(1ull << 63);                // function deactivates (single_f = 1)
    atomicAdd(&tmp[v0], 0x10000u | (unsigned int)((g >> 60) & 1u));
    atomicAdd(&tmp[v1], 0x10000u | (unsigned int)((g >> 61) & 1u));
    atomicAdd(&tmp[v2], 0x10000u | (unsigned int)((g >> 62) & 1u));
    tgrp[v0 >> 6] = 1; tgrp[v1 >> 6] = 1; tgrp[v2 >> 6] = 1;
}

__global__ __launch_bounds__(256) void k_funcs(unsigned long long* __restrict__ gpack,
                        const unsigned int* __restrict__ svm32,
                        const unsigned char* __restrict__ sgrp8,
                        unsigned int* __restrict__ tmp,
                        unsigned char* __restrict__ tgrp)
{
    __shared__ __align__(16) unsigned char s8[AVW];        // 15.7 KB, AVW % 16 == 0
    for (int i = threadIdx.x; i < AVW / 16; i += 256)
        ((int4*)s8)[i] = ((const int4*)sgrp8)[i];
    __syncthreads();
    const int gid = blockIdx.x * 256 + threadIdx.x;
    const int f = 8 * gid;
    if (f >= Fn) return;                                   // Fn % 8 == 0: no partial
    ulonglong2 ga = *(const ulonglong2*)(gpack + f);       // 16B aligned
    ulonglong2 gb = *(const ulonglong2*)(gpack + f + 2);
    ulonglong2 gc = *(const ulonglong2*)(gpack + f + 4);
    ulonglong2 gd = *(const ulonglong2*)(gpack + f + 6);
    fire_one(ga.x, f,     gpack, svm32, s8, tmp, tgrp);
    fire_one(ga.y, f + 1, gpack, svm32, s8, tmp, tgrp);
    fire_one(gb.x, f + 2, gpack, svm32, s8, tmp, tgrp);
    fire_one(gb.y, f + 3, gpack, svm32, s8, tmp, tgrp);
    fire_one(gc.x, f + 4, gpack, svm32, s8, tmp, tgrp);
    fire_one(gc.y, f + 5, gpack, svm32, s8, tmp, tgrp);
    fire_one(gd.x, f + 6, gpack, svm32, s8, tmp, tgrp);
    fire_one(gd.y, f + 7, gpack, svm32, s8, tmp, tgrp);
}

// ---- iteration: variable side. Clean-word early-exit; masks + sgrp8 refresh. ----
__global__ void k_update(unsigned int* __restrict__ packed,
                         unsigned int* __restrict__ tmp,
                         unsigned long long* __restrict__ avm,
                         unsigned long long* __restrict__ svm,
                         unsigned char* __restrict__ sgrp8,
                         unsigned char* __restrict__ tgrp,
                         float* __restrict__ deg, int write_deg)
{
    const int v = blockIdx.x * blockDim.x + threadIdx.x;
    const int lane = threadIdx.x & 63;
    const bool valid = v < Vn;
    unsigned long long avw = 0ull, svw = 0ull;
    unsigned char tg = 0;
    if (valid) {
        avw = avm[v >> 6]; svw = svm[v >> 6];          // wave-broadcast loads
        tg = tgrp[v >> 6];                             // wave-uniform dirty-group byte
    }
    // clean word: no fired updates, no singles to retire -> provably no state change
    // (its previous k_update/k_accum write already left svm=0, sgrp8=0)
    if (!write_deg && !tg && svw == 0ull) return;
    const bool av_old = valid && ((avw >> lane) & 1ull);
    const bool sv     = valid && ((svw >> lane) & 1ull);
    const bool av_new = av_old && !sv;                  // av *= (1 - single_v)
    unsigned int p = 0u;
    if (valid) {
        p = packed[v];
        if (tg) {
            unsigned int tp = tmp[v];
            if (tp != 0u) {
                if (av_old) { p -= tp; packed[v] = p; } // deg -= seg*av (field-safe)
                tmp[v] = 0u;
            }
        }
    }
    const unsigned int c = p >> 16, pos = p & 0xFFFFu;
    const bool nsv = av_new && (pos == 0u || pos == c); // next single_v
    unsigned long long nsvb = __ballot(nsv);
    if (lane == 0 && valid) {
        svm[v >> 6] = nsvb;
        avm[v >> 6] = avw & ~svw;
        sgrp8[v >> 6] = subdirty8(nsvb);
        if (tg) tgrp[v >> 6] = 0;
    }
    if (write_deg && valid) deg[v] = (float)c;
}

extern "C" void kernel_launch(void* const* d_in, const int* in_sizes, int n_in,
                              void* d_out, int out_size, void* d_ws, size_t ws_size,
                              hipStream_t stream) {
    const int*   graph_map        = (const int*)d_in[0];   // row0 = vidx
    const float* edge_feature     = (const float*)d_in[1];
    const float* active_variables = (const float*)d_in[2];
    const float* active_functions = (const float*)d_in[3];
    const int* vidx = graph_map;

    float* deg = (float*)d_out;
    char* ws = (char*)d_ws;
    size_t off = 0;
    auto alloc = [&](size_t bytes) -> void* {
        void* p = ws + off; off += (bytes + 255) & ~(size_t)255; return p;
    };
    unsigned long long* gpack = (unsigned long long*)alloc(8ull * Fn);            // 33.6 MB
    unsigned int* packed      = (unsigned int*)alloc(4ull * Vn);                  //  4.0 MB
    unsigned long long* avm   = (unsigned long long*)alloc(8ull * AVW);           //  125 KB
    unsigned long long* svm   = (unsigned long long*)alloc(8ull * AVW);           //  125 KB
    unsigned char* sgrp8      = (unsigned char*)alloc(AVW);                       // 15.7 KB
    unsigned char* tgrp       = (unsigned char*)alloc(AVW);                       // 15.7 KB
    unsigned short* offs      = (unsigned short*)alloc(2ull * SBLK * OROW);       //  4.2 MB
    unsigned short* offs_T    = (unsigned short*)alloc(2ull * SBLK * OROW);       //  4.2 MB
    unsigned short* sorted    = (unsigned short*)alloc(2ull * SBLK * RSTRIDE);    // 25.4 MB
    unsigned int* tmp         = (unsigned int*)alloc(4ull * Vn);                  //  4.0 MB
    // total ~75.7 MB (R12 used this much and passed)

    const int BS = 256;
    const int gV = (Vn + BS - 1) / BS;
    const int gF8 = (Fn / 8 + BS - 1) / BS;

    k_pack_sort<<<SBLK, 256, 0, stream>>>(vidx, edge_feature, active_functions,
                                          gpack, offs, sorted, tmp, tgrp);
    k_transpose<<<dim3(OROW / 64, SBLK / 64), 256, 0, stream>>>(offs, offs_T);
    k_accum<<<NCH, 1024, 0, stream>>>(offs_T, sorted, active_variables, packed, avm, svm, sgrp8);
    for (int t = 0; t < Tn; ++t) {
        k_funcs<<<gF8, BS, 0, stream>>>(gpack, (const unsigned int*)svm, sgrp8, tmp, tgrp);
        k_update<<<gV, BS, 0, stream>>>(packed, tmp, avm, svm, sgrp8, tgrp, deg, (t == Tn - 1) ? 1 : 0);
    }
}